// Round 5
// baseline (46.858 us; speedup 1.0000x reference)
//
#include <hip/hip_runtime.h>

#define BB      256
#define NVAR    10000
#define NCLAUSE 40000
#define NNODE   50000
#define NT      1024
#define NG8     (NCLAUSE / 8)    // 5000 vec8 clause groups per row
#define NV4V    (NVAR / 4)       // 2500 vec4 var groups per row
#define LDSW    2504             // 10016 bytes of LDS flags (word-addressed)

// ws layout: float accum @0, unsigned counter @8; memset 16B each call.

__device__ __forceinline__ float softplusf(float x) {
    // stable softplus: max(x,0) + log(1+exp(-|x|))
    return fmaxf(x, 0.f) + __logf(1.f + __expf(-fabsf(x)));
}

__global__ __launch_bounds__(NT) void k_all(const float* __restrict__ outp,
                                            const float* __restrict__ yp,
                                            const int*   __restrict__ cl,
                                            float* __restrict__ accum,
                                            unsigned* __restrict__ counter,
                                            float* __restrict__ res) {
    __shared__ unsigned fw[LDSW];         // byte flags for this row
    __shared__ float red[NT / 64];
    const int b = blockIdx.x;
    const int tid = threadIdx.x;
    unsigned char* flags = (unsigned char*)fw;

    for (int i = tid; i < LDSW; i += NT) fw[i] = 0u;
    __syncthreads();

    // ---- clause pass: 8 clauses per thread-iteration (10x 16B loads in flight) ----
    const float* orow = outp + (size_t)b * NNODE + NVAR;
    const float* yrow = yp   + (size_t)b * NNODE + NVAR;
    const int*   crow = cl   + (size_t)b * NCLAUSE * 3;

    float s1 = 0.f;
    for (int t = tid; t < NG8; t += NT) {
        float o[8], y[8];
        {
            const float4 a0 = *(const float4*)(orow + 8 * t);
            const float4 a1 = *(const float4*)(orow + 8 * t + 4);
            const float4 b0 = *(const float4*)(yrow + 8 * t);
            const float4 b1 = *(const float4*)(yrow + 8 * t + 4);
            o[0]=a0.x; o[1]=a0.y; o[2]=a0.z; o[3]=a0.w;
            o[4]=a1.x; o[5]=a1.y; o[6]=a1.z; o[7]=a1.w;
            y[0]=b0.x; y[1]=b0.y; y[2]=b0.z; y[3]=b0.w;
            y[4]=b1.x; y[5]=b1.y; y[6]=b1.z; y[7]=b1.w;
        }
        int idx[24];
        {
            const int4* cp = (const int4*)(crow + 24 * t);
            #pragma unroll
            for (int k = 0; k < 6; ++k) {
                const int4 v = cp[k];
                idx[4*k] = v.x; idx[4*k+1] = v.y; idx[4*k+2] = v.z; idx[4*k+3] = v.w;
            }
        }
        #pragma unroll
        for (int j = 0; j < 8; ++j) {
            s1 += softplusf(o[j]) - o[j] * y[j];
            if (o[j] > 0.f) {
                flags[idx[3*j]] = 1; flags[idx[3*j+1]] = 1; flags[idx[3*j+2]] = 1;
            }
        }
    }
    __syncthreads();

    // ---- var pass: S2 from out[b,0:NVAR] vs LDS flags ----
    float s2 = 0.f;
    {
        const float* vrow = outp + (size_t)b * NNODE;
        for (int v = tid; v < NV4V; v += NT) {
            const float4 q4 = *(const float4*)(vrow + 4 * v);
            const unsigned f = fw[v];          // 4 flag bytes per u32, stride-1
            s2 += softplusf(q4.x) - q4.x * (float)( f        & 1u);
            s2 += softplusf(q4.y) - q4.y * (float)((f >> 8)  & 1u);
            s2 += softplusf(q4.z) - q4.z * (float)((f >> 16) & 1u);
            s2 += softplusf(q4.w) - q4.w * (float)((f >> 24) & 1u);
        }
    }

    // ---- block reduce pre-scaled contribution, then counter-gated finalize ----
    float v = s1 * (1.0f / ((float)NNODE * (float)NCLAUSE)) + s2 * (2.0f / (float)NNODE);
    #pragma unroll
    for (int off = 32; off; off >>= 1) v += __shfl_down(v, off, 64);
    const int lane = tid & 63, w = tid >> 6;
    if (lane == 0) red[w] = v;
    __syncthreads();
    if (tid == 0) {
        float r = 0.f;
        #pragma unroll
        for (int i = 0; i < NT / 64; ++i) r += red[i];
        atomicAdd(accum, r);
        __threadfence();                       // order accum add before counter bump
        const unsigned old = atomicAdd(counter, 1u);
        if (old == BB - 1) {                   // last block finalizes
            const float S = atomicAdd(accum, 0.0f);   // device-coherent read
            const double ln2 = 0.6931471805599453;
            double rr = (double)S
                      + ((double)BB * NVAR * ln2) / ((double)NNODE * (double)NCLAUSE)
                      + 2.0 * ((double)BB * NCLAUSE * ln2) / (double)NNODE;
            res[0] = (float)rr;
        }
    }
}

extern "C" void kernel_launch(void* const* d_in, const int* in_sizes, int n_in,
                              void* d_out, int out_size, void* d_ws, size_t ws_size,
                              hipStream_t stream) {
    const float* outp = (const float*)d_in[0];
    const float* yp   = (const float*)d_in[1];
    // d_in[2] = mask: structurally [zeros(NVAR) | ones(NCLAUSE)] — never read.
    const int* cl     = (const int*)d_in[3];

    float* accum = (float*)d_ws;
    unsigned* counter = (unsigned*)((char*)d_ws + 8);
    hipMemsetAsync(d_ws, 0, 16, stream);   // zero accum + counter each call

    k_all<<<BB, NT, 0, stream>>>(outp, yp, cl, accum, counter, (float*)d_out);
}

// Round 6
// 45.779 us; speedup vs baseline: 1.0236x; 1.0236x over previous
//
#include <hip/hip_runtime.h>

#define BB      256
#define NVAR    10000
#define NCLAUSE 40000
#define NNODE   50000
#define NT      1024
#define NV4C    (NCLAUSE / 4)    // 10000 vec4 clause groups per row
#define NV4V    (NVAR / 4)       // 2500 vec4 var groups per row
#define LDSW    2504             // 10016 bytes of LDS byte-flags, word-addressed

// ws layout: float accum @0, unsigned counter @8; memset 16B each call.

__device__ __forceinline__ float softplusf(float x) {
    // stable softplus: max(x,0) + log(1+exp(-|x|))
    return fmaxf(x, 0.f) + __logf(1.f + __expf(-fabsf(x)));
}

__device__ __forceinline__ float bce4(const float4 q, const unsigned f) {
    float s = 0.f;
    s += softplusf(q.x) - q.x * (float)( f        & 1u);
    s += softplusf(q.y) - q.y * (float)((f >> 8)  & 1u);
    s += softplusf(q.z) - q.z * (float)((f >> 16) & 1u);
    s += softplusf(q.w) - q.w * (float)((f >> 24) & 1u);
    return s;
}

__global__ __launch_bounds__(NT) void k_all(const float* __restrict__ outp,
                                            const float* __restrict__ yp,
                                            const int*   __restrict__ cl,
                                            float* __restrict__ accum,
                                            unsigned* __restrict__ counter,
                                            float* __restrict__ res) {
    __shared__ unsigned fw[LDSW];         // byte flags for this row
    __shared__ float red[NT / 64];
    const int b = blockIdx.x;
    const int tid = threadIdx.x;
    unsigned char* flags = (unsigned char*)fw;

    for (int i = tid; i < LDSW; i += NT) fw[i] = 0u;
    __syncthreads();

    // ---- hoist var-part loads (flag-independent) into registers ----
    const float4* vrow4 = (const float4*)(outp + (size_t)b * NNODE);
    const bool h1 = (tid + NT     < NV4V);
    const bool h2 = (tid + 2 * NT < NV4V);
    float4 q0, q1, q2;
    q0 = vrow4[tid];
    if (h1) q1 = vrow4[tid + NT];
    if (h2) q2 = vrow4[tid + 2 * NT];

    // ---- clause pass: S1 + LDS flag scatter (R2's loop — best-scheduled) ----
    const float* orow = outp + (size_t)b * NNODE + NVAR;
    const float* yrow = yp   + (size_t)b * NNODE + NVAR;
    const int*   crow = cl   + (size_t)b * NCLAUSE * 3;

    float s1 = 0.f;
    for (int t = tid; t < NV4C; t += NT) {
        const float4 o4 = *(const float4*)(orow + 4 * t);
        const float4 y4 = *(const float4*)(yrow + 4 * t);
        const int4* cp = (const int4*)(crow + 12 * t);
        const int4 c0 = cp[0], c1 = cp[1], c2 = cp[2];

        s1 += softplusf(o4.x) - o4.x * y4.x;
        s1 += softplusf(o4.y) - o4.y * y4.y;
        s1 += softplusf(o4.z) - o4.z * y4.z;
        s1 += softplusf(o4.w) - o4.w * y4.w;

        if (o4.x > 0.f) { flags[c0.x] = 1; flags[c0.y] = 1; flags[c0.z] = 1; }
        if (o4.y > 0.f) { flags[c0.w] = 1; flags[c1.x] = 1; flags[c1.y] = 1; }
        if (o4.z > 0.f) { flags[c1.z] = 1; flags[c1.w] = 1; flags[c2.x] = 1; }
        if (o4.w > 0.f) { flags[c2.y] = 1; flags[c2.z] = 1; flags[c2.w] = 1; }
    }
    __syncthreads();

    // ---- var pass: LDS flags vs preloaded registers (no global loads here) ----
    float s2 = bce4(q0, fw[tid]);
    if (h1) s2 += bce4(q1, fw[tid + NT]);
    if (h2) s2 += bce4(q2, fw[tid + 2 * NT]);

    // ---- block reduce pre-scaled contribution, counter-gated finalize ----
    float v = s1 * (1.0f / ((float)NNODE * (float)NCLAUSE)) + s2 * (2.0f / (float)NNODE);
    #pragma unroll
    for (int off = 32; off; off >>= 1) v += __shfl_down(v, off, 64);
    const int lane = tid & 63, w = tid >> 6;
    if (lane == 0) red[w] = v;
    __syncthreads();
    if (tid == 0) {
        float r = 0.f;
        #pragma unroll
        for (int i = 0; i < NT / 64; ++i) r += red[i];
        atomicAdd(accum, r);
        __threadfence();                       // order accum add before counter bump
        const unsigned old = atomicAdd(counter, 1u);
        if (old == BB - 1) {                   // last block finalizes
            const float S = atomicAdd(accum, 0.0f);   // device-coherent read
            const double ln2 = 0.6931471805599453;
            double rr = (double)S
                      + ((double)BB * NVAR * ln2) / ((double)NNODE * (double)NCLAUSE)
                      + 2.0 * ((double)BB * NCLAUSE * ln2) / (double)NNODE;
            res[0] = (float)rr;
        }
    }
}

extern "C" void kernel_launch(void* const* d_in, const int* in_sizes, int n_in,
                              void* d_out, int out_size, void* d_ws, size_t ws_size,
                              hipStream_t stream) {
    const float* outp = (const float*)d_in[0];
    const float* yp   = (const float*)d_in[1];
    // d_in[2] = mask: structurally [zeros(NVAR) | ones(NCLAUSE)] — never read.
    const int* cl     = (const int*)d_in[3];

    float* accum = (float*)d_ws;
    unsigned* counter = (unsigned*)((char*)d_ws + 8);
    hipMemsetAsync(d_ws, 0, 16, stream);   // zero accum + counter each call

    k_all<<<BB, NT, 0, stream>>>(outp, yp, cl, accum, counter, (float*)d_out);
}